// Round 6
// baseline (1472.086 us; speedup 1.0000x reference)
//
#include <hip/hip_runtime.h>

// Problem constants: N=100000 nodes, E=1.6M edges, D=128, H=O=64.
constexpr int FD = 64;    // feature dim of both layers
constexpr int P  = 8;     // level-1 dst buckets (~XCDs)
constexpr int WN = 125;   // nodes per window (level-2); 125*64*4B = 32KB LDS tile
constexpr int SRC_BITS = 17;                 // src id fits 17 bits (N <= 131072)
constexpr int SRC_MASK = (1 << SRC_BITS) - 1;

__device__ __forceinline__ int part_of(int d, unsigned long long M) {
    return (int)(((unsigned long long)(unsigned)d * M) >> 32);  // == d / npp
}

// ---------------- init per-call cursors (replaces memsets) -------------------
__global__ void k_init(int* __restrict__ gcur1, int cap1,
                       int* __restrict__ gcur2, int cap2, int NW) {
    int i = blockIdx.x * 1024 + threadIdx.x;
    if (i < P)  gcur1[i] = i * cap1;
    if (i < NW) gcur2[i] = i * cap2;
}

// ---------------- level 1: 8-way split by dst range, packed output -----------
// p1[pos] = ((d - bucket*npp) << 17) | s   (dl < 16384, s < 2^17)
__global__ __launch_bounds__(256) void k_part8(const int* __restrict__ src,
                                               const int* __restrict__ dst, int E,
                                               unsigned long long M, int npp,
                                               int* __restrict__ gcur1, int cap1,
                                               int* __restrict__ p1) {
    constexpr int CH = 4096;
    __shared__ int hh[P], bbase[P], lcur[P];
    if (threadIdx.x < P) hh[threadIdx.x] = 0;
    __syncthreads();
    const int e0 = blockIdx.x * CH;
    const int e1 = min(e0 + CH, E);
    const int lane = threadIdx.x & 63;
    for (int base = e0; base < e1; base += 256) {
        int e = base + threadIdx.x;
        bool valid = e < e1;
        int b = 0;
        if (valid) b = part_of(__builtin_nontemporal_load(&dst[e]), M);
#pragma unroll
        for (int q = 0; q < P; ++q) {
            unsigned long long m = __ballot(valid && b == q);
            if (m && lane == 0) atomicAdd(&hh[q], __popcll(m));
        }
    }
    __syncthreads();
    if (threadIdx.x < P) {
        bbase[threadIdx.x] = atomicAdd(&gcur1[threadIdx.x], hh[threadIdx.x]);
        lcur[threadIdx.x] = 0;
    }
    __syncthreads();
    for (int base = e0; base < e1; base += 256) {
        int e = base + threadIdx.x;
        bool valid = e < e1;
        int d = 0, s = 0, b = 0;
        if (valid) { d = dst[e]; s = src[e]; b = part_of(d, M); }
#pragma unroll
        for (int q = 0; q < P; ++q) {
            unsigned long long m = __ballot(valid && b == q);
            if (!m) continue;
            int leader = __ffsll((unsigned long long)m) - 1;
            int wbase = 0;
            if (lane == leader) wbase = atomicAdd(&lcur[q], __popcll(m));
            wbase = __shfl(wbase, leader, 64);
            if (valid && b == q) {
                int rank = __popcll(m & ((1ull << lane) - 1));
                int pos = bbase[q] + wbase + rank;
                if (pos < (q + 1) * cap1)
                    p1[pos] = ((d - q * npp) << SRC_BITS) | s;
            }
        }
    }
}

// ---------------- level 2: split bucket into 125-node windows ----------------
// p2[pos] = (local_dst << 17) | s, grouped by window (fixed-cap regions).
__global__ __launch_bounds__(256) void k_partwin(const int* __restrict__ p1,
                                                 const int* __restrict__ gcur1, int cap1,
                                                 int npp,
                                                 int* __restrict__ gcur2, int cap2,
                                                 int* __restrict__ p2) {
    constexpr int CH = 4096;
    constexpr int MAXW = 128;
    __shared__ int hh[MAXW], wbase[MAXW], lcur[MAXW];
    const int p   = blockIdx.x & (P - 1);
    const int j   = blockIdx.x >> 3;
    const int wlo = (p * npp) / WN;
    const int whi = ((p + 1) * npp - 1) / WN;
    const int nw  = whi - wlo + 1;             // <= 101
    for (int t = threadIdx.x; t < nw; t += 256) hh[t] = 0;
    __syncthreads();
    const int lo = p * cap1 + j * CH;
    const int hi = min(lo + CH, gcur1[p]);
    if (lo >= hi) return;
    // pass 1: histogram over windows
    for (int e = lo + threadIdx.x; e < hi; e += 256) {
        int pk = __builtin_nontemporal_load(&p1[e]);
        int d  = p * npp + (pk >> SRC_BITS);
        atomicAdd(&hh[d / WN - wlo], 1);
    }
    __syncthreads();
    for (int t = threadIdx.x; t < nw; t += 256) {
        wbase[t] = hh[t] ? atomicAdd(&gcur2[wlo + t], hh[t]) : 0;
        lcur[t] = 0;
    }
    __syncthreads();
    // pass 2: scatter (chunk re-read is L2-hit)
    for (int e = lo + threadIdx.x; e < hi; e += 256) {
        int pk = p1[e];
        int s  = pk & SRC_MASK;
        int d  = p * npp + (pk >> SRC_BITS);
        int w  = d / WN;
        int hw = w - wlo;
        int pos = wbase[hw] + atomicAdd(&lcur[hw], 1);
        if (pos < (w + 1) * cap2)
            p2[pos] = ((d - w * WN) << SRC_BITS) | s;
    }
}

// ---------------- per-window degree -> dinv (LDS hist, contiguous writes) ----
__global__ __launch_bounds__(256) void k_deg_win(const int* __restrict__ p2,
                                                 const int* __restrict__ gcur2, int cap2,
                                                 float* __restrict__ dinv, int N) {
    __shared__ int hist[WN];
    const int w = blockIdx.x;
    for (int t = threadIdx.x; t < WN; t += 256) hist[t] = 0;
    __syncthreads();
    const int lo = w * cap2;
    const int hi = min(gcur2[w], lo + cap2);
    for (int e = lo + threadIdx.x; e < hi; e += 256)
        atomicAdd(&hist[__builtin_nontemporal_load(&p2[e]) >> SRC_BITS], 1);
    __syncthreads();
    for (int t = threadIdx.x; t < WN; t += 256) {
        int node = w * WN + t;
        if (node < N) dinv[node] = rsqrtf((float)(hist[t] + 1));  // +1 self-loop
    }
}

// ---------------- register-tiled GEMM: Y = dinv .* (act(X) @ W) --------------
template <int K, bool RELU>
__global__ __launch_bounds__(256) void k_gemm(const float* __restrict__ X,
                                              const float* __restrict__ W,
                                              const float* __restrict__ dinv,
                                              float* __restrict__ Y, int n) {
    constexpr int ASTR = 260;
    __shared__ __align__(16) float Bs[K * FD];
    __shared__ __align__(16) float As[32 * ASTR];
    for (int i = threadIdx.x; i < K * FD / 4; i += 256)
        ((float4*)Bs)[i] = ((const float4*)W)[i];

    const int rt   = threadIdx.x >> 3;
    const int ct   = threadIdx.x & 7;
    const int row0 = blockIdx.x * 256;
    float acc[8][8] = {};

    for (int kp = 0; kp < K; kp += 32) {
        __syncthreads();
        const int mq = threadIdx.x >> 3;
        const int q  = threadIdx.x & 7;
        float4 tv[8];
#pragma unroll
        for (int pass = 0; pass < 8; ++pass) {
            int grow = row0 + mq + pass * 32;
            float4 v = make_float4(0.f, 0.f, 0.f, 0.f);
            if (grow < n) {
                v = *(const float4*)&X[(size_t)grow * K + kp + q * 4];
                if (RELU) {
                    v.x = fmaxf(v.x, 0.f); v.y = fmaxf(v.y, 0.f);
                    v.z = fmaxf(v.z, 0.f); v.w = fmaxf(v.w, 0.f);
                }
            }
            tv[pass] = v;
        }
#pragma unroll
        for (int pass = 0; pass < 8; ++pass) {
            int m = mq + pass * 32;
            As[(q * 4 + 0) * ASTR + m] = tv[pass].x;
            As[(q * 4 + 1) * ASTR + m] = tv[pass].y;
            As[(q * 4 + 2) * ASTR + m] = tv[pass].z;
            As[(q * 4 + 3) * ASTR + m] = tv[pass].w;
        }
        __syncthreads();
#pragma unroll 8
        for (int k = 0; k < 32; ++k) {
            float4 a0 = *(const float4*)&As[k * ASTR + rt * 8];
            float4 a1 = *(const float4*)&As[k * ASTR + rt * 8 + 4];
            float4 b0 = *(const float4*)&Bs[(kp + k) * FD + ct * 8];
            float4 b1 = *(const float4*)&Bs[(kp + k) * FD + ct * 8 + 4];
            float af[8] = {a0.x, a0.y, a0.z, a0.w, a1.x, a1.y, a1.z, a1.w};
            float bf[8] = {b0.x, b0.y, b0.z, b0.w, b1.x, b1.y, b1.z, b1.w};
#pragma unroll
            for (int i = 0; i < 8; ++i)
#pragma unroll
                for (int j = 0; j < 8; ++j)
                    acc[i][j] = fmaf(af[i], bf[j], acc[i][j]);
        }
    }
#pragma unroll
    for (int i = 0; i < 8; ++i) {
        int r = row0 + rt * 8 + i;
        if (r < n) {
            float sc = dinv[r];
            float4 o0 = make_float4(acc[i][0] * sc, acc[i][1] * sc,
                                    acc[i][2] * sc, acc[i][3] * sc);
            float4 o1 = make_float4(acc[i][4] * sc, acc[i][5] * sc,
                                    acc[i][6] * sc, acc[i][7] * sc);
            *(float4*)&Y[(size_t)r * FD + ct * 8]     = o0;
            *(float4*)&Y[(size_t)r * FD + ct * 8 + 4] = o1;
        }
    }
}

// ---------------- windowed aggregation: LDS-atomic accumulate ----------------
// One block per 125-node window. o[ld][*] += A'[src]; swizzled float index
// (4*lane + c + ld) & 63 spreads the 4-aligned pattern over all 32 banks.
// out[d] = dinv[d] * (o[d] + A'[d]) + bias.
__global__ __launch_bounds__(512) void k_aggw(const float* __restrict__ X,
                                              const int* __restrict__ p2,
                                              const int* __restrict__ gcur2, int cap2,
                                              const float* __restrict__ dinv,
                                              const float* __restrict__ bias,
                                              float* __restrict__ out, int N) {
    __shared__ float o[WN * FD];   // 32000 B
    const int w = blockIdx.x;
    for (int i = threadIdx.x; i < WN * FD; i += 512) o[i] = 0.f;
    __syncthreads();
    const int lo = w * cap2;
    const int hi = min(gcur2[w], lo + cap2);
    const int g    = threadIdx.x >> 4;   // 32 groups of 16 lanes
    const int lane = threadIdx.x & 15;
    const float4* Xv = (const float4*)X;
    const int l4 = lane * 4;
    for (int e = lo + g; e < hi; e += 64) {
        int pk1 = p2[e];
        int e2  = e + 32;
        int pk2 = (e2 < hi) ? p2[e2] : -1;
        float4 v1 = Xv[(size_t)(pk1 & SRC_MASK) * 16 + lane];
        float4 v2 = (pk2 >= 0) ? Xv[(size_t)(pk2 & SRC_MASK) * 16 + lane]
                               : make_float4(0.f, 0.f, 0.f, 0.f);
        int ld1 = pk1 >> SRC_BITS, r1 = ld1 << 6;
        atomicAdd(&o[r1 + ((l4 + 0 + ld1) & 63)], v1.x);
        atomicAdd(&o[r1 + ((l4 + 1 + ld1) & 63)], v1.y);
        atomicAdd(&o[r1 + ((l4 + 2 + ld1) & 63)], v1.z);
        atomicAdd(&o[r1 + ((l4 + 3 + ld1) & 63)], v1.w);
        if (pk2 >= 0) {
            int ld2 = pk2 >> SRC_BITS, r2 = ld2 << 6;
            atomicAdd(&o[r2 + ((l4 + 0 + ld2) & 63)], v2.x);
            atomicAdd(&o[r2 + ((l4 + 1 + ld2) & 63)], v2.y);
            atomicAdd(&o[r2 + ((l4 + 2 + ld2) & 63)], v2.z);
            atomicAdd(&o[r2 + ((l4 + 3 + ld2) & 63)], v2.w);
        }
    }
    __syncthreads();
    const int n0 = w * WN;
    for (int i = threadIdx.x; i < WN * 16; i += 512) {
        int r = i >> 4, l = i & 15;
        int node = n0 + r;
        if (node < N) {
            int rr = r << 6, lq = l * 4;
            float ax = o[rr + ((lq + 0 + r) & 63)];
            float ay = o[rr + ((lq + 1 + r) & 63)];
            float az = o[rr + ((lq + 2 + r) & 63)];
            float aw = o[rr + ((lq + 3 + r) & 63)];
            float4 sv = Xv[(size_t)node * 16 + l];
            float di = dinv[node];
            float4 bb = ((const float4*)bias)[l];
            float4 oo;
            oo.x = fmaf(di, ax + sv.x, bb.x);
            oo.y = fmaf(di, ay + sv.y, bb.y);
            oo.z = fmaf(di, az + sv.z, bb.z);
            oo.w = fmaf(di, aw + sv.w, bb.w);
            ((float4*)(out + (size_t)node * FD))[l] = oo;
        }
    }
}

// ---------------- launch ----------------

extern "C" void kernel_launch(void* const* d_in, const int* in_sizes, int n_in,
                              void* d_out, int out_size, void* d_ws, size_t ws_size,
                              hipStream_t stream) {
    const float* emb = (const float*)d_in[0];
    const float* W1  = (const float*)d_in[1];
    const float* b1  = (const float*)d_in[2];
    const float* W2  = (const float*)d_in[3];
    const float* b2  = (const float*)d_in[4];
    const int*   src = (const int*)d_in[5];
    const int*   dst = (const int*)d_in[6];

    const int D = 128;
    const int N = in_sizes[0] / D;   // 100000
    const int E = in_sizes[5];       // 1.6M
    float* out = (float*)d_out;

    const int npp  = (N + P - 1) / P;          // 12500 (< 2^14 for packing)
    const int NW   = (N + WN - 1) / WN;        // 800 windows
    const int cap1 = E / P + 16384;            // level-1 bucket capacity
    const int cap2 = E / NW + 560;             // window capacity (~12 sigma)
    const unsigned long long M = ((1ull << 32) + npp - 1) / npp;

    // workspace (ints/floats are 4B): A | p2 | dinv | gcur1 | gcur2 ; p1 aliases A
    float* A     = (float*)d_ws;                       // N*FD
    int*   p2    = (int*)(A + (size_t)N * FD);         // NW*cap2
    float* dinv  = (float*)(p2 + (size_t)NW * cap2);   // N
    int*   gcur1 = (int*)(dinv + N);                   // P
    int*   gcur2 = gcur1 + P;                          // NW
    int*   p1    = (int*)A;                            // P*cap1 (fits in A)

    k_init<<<(NW + 1023) / 1024, 1024, 0, stream>>>(gcur1, cap1, gcur2, cap2, NW);
    k_part8<<<(E + 4095) / 4096, 256, 0, stream>>>(src, dst, E, M, npp, gcur1, cap1, p1);
    int nb2 = (cap1 + 4095) / 4096;
    k_partwin<<<P * nb2, 256, 0, stream>>>(p1, gcur1, cap1, npp, gcur2, cap2, p2);
    k_deg_win<<<NW, 256, 0, stream>>>(p2, gcur2, cap2, dinv, N);

    int gblocks = (N + 255) / 256;
    // layer 1: A' = dinv.*(emb @ W1); h = dinv.*(sum_win A' + A'[self]) + b1
    k_gemm<128, false><<<gblocks, 256, 0, stream>>>(emb, W1, dinv, A, N);
    k_aggw<<<NW, 512, 0, stream>>>(A, p2, gcur2, cap2, dinv, b1, out, N);
    // layer 2: A'' = dinv.*(relu(h) @ W2); out = dinv.*(sum_win A'' + self) + b2
    k_gemm<64, true><<<gblocks, 256, 0, stream>>>(out, W2, dinv, A, N);
    k_aggw<<<NW, 512, 0, stream>>>(A, p2, gcur2, cap2, dinv, b2, out, N);
}

// Round 7
// 273.689 us; speedup vs baseline: 5.3787x; 5.3787x over previous
//
#include <hip/hip_runtime.h>

// Problem constants: N=100000 nodes, E=1.6M edges, D=128, H=O=64.
constexpr int FD = 64;    // feature dim of both layers
constexpr int P  = 8;     // level-1 dst buckets (~XCDs)
constexpr int WN = 125;   // nodes per window (level-2)
constexpr int SRC_BITS = 17;                 // src id fits 17 bits (N <= 131072)
constexpr int SRC_MASK = (1 << SRC_BITS) - 1;

__device__ __forceinline__ int part_of(int d, unsigned long long M) {
    return (int)(((unsigned long long)(unsigned)d * M) >> 32);  // == d / npp
}

// ---------------- init per-call cursors -------------------------------------
__global__ void k_init(int* __restrict__ gcur1, int cap1,
                       int* __restrict__ gcur2, int cap2, int NW) {
    int i = threadIdx.x;
    if (i < P)  gcur1[i] = i * cap1;
    if (i < NW) gcur2[i] = i * cap2;
}

// ---------------- level 1: 8-way split by dst range, packed output -----------
// p1[pos] = ((d - bucket*npp) << 17) | s
__global__ __launch_bounds__(256) void k_part8(const int* __restrict__ src,
                                               const int* __restrict__ dst, int E,
                                               unsigned long long M, int npp,
                                               int* __restrict__ gcur1, int cap1,
                                               int* __restrict__ p1) {
    constexpr int CH = 4096;
    __shared__ int hh[P], bbase[P], lcur[P];
    if (threadIdx.x < P) hh[threadIdx.x] = 0;
    __syncthreads();
    const int e0 = blockIdx.x * CH;
    const int e1 = min(e0 + CH, E);
    const int lane = threadIdx.x & 63;
    for (int base = e0; base < e1; base += 256) {
        int e = base + threadIdx.x;
        bool valid = e < e1;
        int b = 0;
        if (valid) b = part_of(__builtin_nontemporal_load(&dst[e]), M);
#pragma unroll
        for (int q = 0; q < P; ++q) {
            unsigned long long m = __ballot(valid && b == q);
            if (m && lane == 0) atomicAdd(&hh[q], __popcll(m));
        }
    }
    __syncthreads();
    if (threadIdx.x < P) {
        bbase[threadIdx.x] = atomicAdd(&gcur1[threadIdx.x], hh[threadIdx.x]);
        lcur[threadIdx.x] = 0;
    }
    __syncthreads();
    for (int base = e0; base < e1; base += 256) {
        int e = base + threadIdx.x;
        bool valid = e < e1;
        int d = 0, s = 0, b = 0;
        if (valid) { d = dst[e]; s = src[e]; b = part_of(d, M); }
#pragma unroll
        for (int q = 0; q < P; ++q) {
            unsigned long long m = __ballot(valid && b == q);
            if (!m) continue;
            int leader = __ffsll((unsigned long long)m) - 1;
            int wbase = 0;
            if (lane == leader) wbase = atomicAdd(&lcur[q], __popcll(m));
            wbase = __shfl(wbase, leader, 64);
            if (valid && b == q) {
                int rank = __popcll(m & ((1ull << lane) - 1));
                int pos = bbase[q] + wbase + rank;
                if (pos < (q + 1) * cap1)
                    p1[pos] = ((d - q * npp) << SRC_BITS) | s;
            }
        }
    }
}

// ---------------- level 2: split bucket into 125-node windows ----------------
// p2[pos] = (window_local_dst << 17) | s, grouped by window.
__global__ __launch_bounds__(256) void k_partwin(const int* __restrict__ p1,
                                                 const int* __restrict__ gcur1, int cap1,
                                                 int npp,
                                                 int* __restrict__ gcur2, int cap2,
                                                 int* __restrict__ p2) {
    constexpr int CH = 4096;
    constexpr int MAXW = 128;
    __shared__ int hh[MAXW], wbase[MAXW], lcur[MAXW];
    const int p   = blockIdx.x & (P - 1);
    const int j   = blockIdx.x >> 3;
    const int wlo = (p * npp) / WN;
    const int whi = ((p + 1) * npp - 1) / WN;
    const int nw  = whi - wlo + 1;             // <= 101
    for (int t = threadIdx.x; t < nw; t += 256) hh[t] = 0;
    __syncthreads();
    const int lo = p * cap1 + j * CH;
    const int hi = min(lo + CH, gcur1[p]);
    if (lo >= hi) return;
    for (int e = lo + threadIdx.x; e < hi; e += 256) {
        int pk = __builtin_nontemporal_load(&p1[e]);
        int d  = p * npp + (pk >> SRC_BITS);
        atomicAdd(&hh[d / WN - wlo], 1);
    }
    __syncthreads();
    for (int t = threadIdx.x; t < nw; t += 256) {
        wbase[t] = hh[t] ? atomicAdd(&gcur2[wlo + t], hh[t]) : 0;
        lcur[t] = 0;
    }
    __syncthreads();
    for (int e = lo + threadIdx.x; e < hi; e += 256) {
        int pk = p1[e];
        int s  = pk & SRC_MASK;
        int d  = p * npp + (pk >> SRC_BITS);
        int w  = d / WN;
        int hw = w - wlo;
        int pos = wbase[hw] + atomicAdd(&lcur[hw], 1);
        if (pos < (w + 1) * cap2)
            p2[pos] = ((d - w * WN) << SRC_BITS) | s;
    }
}

// ---------------- level 3: in-place counting sort per window -----------------
// One block per window. Loads <=2560 packed edges into registers, LDS
// histogram + wave-scan, scatters src ids back into p2 sorted by local dst
// (random writes confined to this block's 10 KB region -> one writeback).
// Emits rowinfo[node] = beg_local | (deg << 16) and dinv.
__global__ __launch_bounds__(256) void k_sortwin(int* __restrict__ p2,
                                                 const int* __restrict__ gcur2, int cap2,
                                                 int* __restrict__ rowinfo,
                                                 float* __restrict__ dinv, int N) {
    __shared__ int hist[WN], beg[WN], cur[WN];
    const int w  = blockIdx.x;
    const int lo = w * cap2;
    const int hi = min(gcur2[w], lo + cap2);
    const int cnt = hi - lo;
    for (int t = threadIdx.x; t < WN; t += 256) hist[t] = 0;
    __syncthreads();
    int pk[10];                      // cap2 <= 2560 = 10*256 (checked on host)
#pragma unroll
    for (int j = 0; j < 10; ++j) {
        int i = j * 256 + threadIdx.x;
        pk[j] = (i < cnt) ? p2[lo + i] : -1;
        if (pk[j] >= 0) atomicAdd(&hist[pk[j] >> SRC_BITS], 1);
    }
    __syncthreads();
    if (threadIdx.x < 64) {          // wave 0: exclusive scan of hist[0..124]
        int lane = threadIdx.x;
        int v0 = hist[lane];
        int x0 = v0;
#pragma unroll
        for (int o = 1; o < 64; o <<= 1) { int y = __shfl_up(x0, o, 64); if (lane >= o) x0 += y; }
        int tot0 = __shfl(x0, 63, 64);
        int v1 = (lane < WN - 64) ? hist[64 + lane] : 0;
        int x1 = v1;
#pragma unroll
        for (int o = 1; o < 64; o <<= 1) { int y = __shfl_up(x1, o, 64); if (lane >= o) x1 += y; }
        int b0 = x0 - v0;
        beg[lane] = b0; cur[lane] = b0;
        if (lane < WN - 64) {
            int b1 = tot0 + x1 - v1;
            beg[64 + lane] = b1; cur[64 + lane] = b1;
        }
    }
    __syncthreads();
#pragma unroll
    for (int j = 0; j < 10; ++j) {
        if (pk[j] >= 0) {
            int ld  = pk[j] >> SRC_BITS;
            int pos = atomicAdd(&cur[ld], 1);
            p2[lo + pos] = pk[j] & SRC_MASK;   // sorted src id
        }
    }
    for (int t = threadIdx.x; t < WN; t += 256) {
        int node = w * WN + t;
        if (node < N) {
            rowinfo[node] = beg[t] | (hist[t] << 16);
            dinv[node] = rsqrtf((float)(hist[t] + 1));   // +1 self-loop
        }
    }
}

// ---------------- register-tiled GEMM: Y = dinv .* (act(X) @ W) --------------
template <int K, bool RELU>
__global__ __launch_bounds__(256) void k_gemm(const float* __restrict__ X,
                                              const float* __restrict__ W,
                                              const float* __restrict__ dinv,
                                              float* __restrict__ Y, int n) {
    constexpr int ASTR = 260;
    __shared__ __align__(16) float Bs[K * FD];
    __shared__ __align__(16) float As[32 * ASTR];
    for (int i = threadIdx.x; i < K * FD / 4; i += 256)
        ((float4*)Bs)[i] = ((const float4*)W)[i];

    const int rt   = threadIdx.x >> 3;
    const int ct   = threadIdx.x & 7;
    const int row0 = blockIdx.x * 256;
    float acc[8][8] = {};

    for (int kp = 0; kp < K; kp += 32) {
        __syncthreads();
        const int mq = threadIdx.x >> 3;
        const int q  = threadIdx.x & 7;
        float4 tv[8];
#pragma unroll
        for (int pass = 0; pass < 8; ++pass) {
            int grow = row0 + mq + pass * 32;
            float4 v = make_float4(0.f, 0.f, 0.f, 0.f);
            if (grow < n) {
                v = *(const float4*)&X[(size_t)grow * K + kp + q * 4];
                if (RELU) {
                    v.x = fmaxf(v.x, 0.f); v.y = fmaxf(v.y, 0.f);
                    v.z = fmaxf(v.z, 0.f); v.w = fmaxf(v.w, 0.f);
                }
            }
            tv[pass] = v;
        }
#pragma unroll
        for (int pass = 0; pass < 8; ++pass) {
            int m = mq + pass * 32;
            As[(q * 4 + 0) * ASTR + m] = tv[pass].x;
            As[(q * 4 + 1) * ASTR + m] = tv[pass].y;
            As[(q * 4 + 2) * ASTR + m] = tv[pass].z;
            As[(q * 4 + 3) * ASTR + m] = tv[pass].w;
        }
        __syncthreads();
#pragma unroll 8
        for (int k = 0; k < 32; ++k) {
            float4 a0 = *(const float4*)&As[k * ASTR + rt * 8];
            float4 a1 = *(const float4*)&As[k * ASTR + rt * 8 + 4];
            float4 b0 = *(const float4*)&Bs[(kp + k) * FD + ct * 8];
            float4 b1 = *(const float4*)&Bs[(kp + k) * FD + ct * 8 + 4];
            float af[8] = {a0.x, a0.y, a0.z, a0.w, a1.x, a1.y, a1.z, a1.w};
            float bf[8] = {b0.x, b0.y, b0.z, b0.w, b1.x, b1.y, b1.z, b1.w};
#pragma unroll
            for (int i = 0; i < 8; ++i)
#pragma unroll
                for (int j = 0; j < 8; ++j)
                    acc[i][j] = fmaf(af[i], bf[j], acc[i][j]);
        }
    }
#pragma unroll
    for (int i = 0; i < 8; ++i) {
        int r = row0 + rt * 8 + i;
        if (r < n) {
            float sc = dinv[r];
            float4 o0 = make_float4(acc[i][0] * sc, acc[i][1] * sc,
                                    acc[i][2] * sc, acc[i][3] * sc);
            float4 o1 = make_float4(acc[i][4] * sc, acc[i][5] * sc,
                                    acc[i][6] * sc, acc[i][7] * sc);
            *(float4*)&Y[(size_t)r * FD + ct * 8]     = o0;
            *(float4*)&Y[(size_t)r * FD + ct * 8 + 4] = o1;
        }
    }
}

// ---------------- edge aggregation (register accumulate, sorted edges) -------
// X pre-scaled by dinv:  out[d] = dinv[d]*(sum_{src in row d} X[src] + X[d]) + b
__global__ __launch_bounds__(256) void k_agg(const float* __restrict__ X,
                                             const int* __restrict__ col,
                                             const int* __restrict__ rowinfo, int cap2,
                                             const float* __restrict__ dinv,
                                             const float* __restrict__ bias,
                                             float* __restrict__ out, int n) {
    int t = blockIdx.x * 256 + threadIdx.x;
    int node = t >> 4;
    int lane = t & 15;
    if (node >= n) return;
    int info = rowinfo[node];
    int w    = (int)((unsigned)node / WN);
    int beg  = w * cap2 + (info & 0xFFFF);
    int end  = beg + (info >> 16);
    const float4* Xv = (const float4*)X;
    float4 a0 = {0,0,0,0}, a1 = {0,0,0,0}, a2 = {0,0,0,0}, a3 = {0,0,0,0};
    int e = beg;
    for (; e + 4 <= end; e += 4) {
        int s0 = col[e], s1 = col[e + 1], s2 = col[e + 2], s3 = col[e + 3];
        float4 v0 = Xv[(size_t)s0 * 16 + lane];
        float4 v1 = Xv[(size_t)s1 * 16 + lane];
        float4 v2 = Xv[(size_t)s2 * 16 + lane];
        float4 v3 = Xv[(size_t)s3 * 16 + lane];
        a0.x += v0.x; a0.y += v0.y; a0.z += v0.z; a0.w += v0.w;
        a1.x += v1.x; a1.y += v1.y; a1.z += v1.z; a1.w += v1.w;
        a2.x += v2.x; a2.y += v2.y; a2.z += v2.z; a2.w += v2.w;
        a3.x += v3.x; a3.y += v3.y; a3.z += v3.z; a3.w += v3.w;
    }
    for (; e < end; ++e) {
        float4 v = Xv[(size_t)col[e] * 16 + lane];
        a0.x += v.x; a0.y += v.y; a0.z += v.z; a0.w += v.w;
    }
    float4 sv = Xv[(size_t)node * 16 + lane];   // self term
    float sx = a0.x + a1.x + a2.x + a3.x + sv.x;
    float sy = a0.y + a1.y + a2.y + a3.y + sv.y;
    float sz = a0.z + a1.z + a2.z + a3.z + sv.z;
    float sw = a0.w + a1.w + a2.w + a3.w + sv.w;
    float di = dinv[node];
    float4 b = ((const float4*)bias)[lane];
    float4 o;
    o.x = fmaf(di, sx, b.x);
    o.y = fmaf(di, sy, b.y);
    o.z = fmaf(di, sz, b.z);
    o.w = fmaf(di, sw, b.w);
    ((float4*)(out + (size_t)node * FD))[lane] = o;
}

// ---------------- launch ----------------

extern "C" void kernel_launch(void* const* d_in, const int* in_sizes, int n_in,
                              void* d_out, int out_size, void* d_ws, size_t ws_size,
                              hipStream_t stream) {
    const float* emb = (const float*)d_in[0];
    const float* W1  = (const float*)d_in[1];
    const float* b1  = (const float*)d_in[2];
    const float* W2  = (const float*)d_in[3];
    const float* b2  = (const float*)d_in[4];
    const int*   src = (const int*)d_in[5];
    const int*   dst = (const int*)d_in[6];

    const int D = 128;
    const int N = in_sizes[0] / D;   // 100000
    const int E = in_sizes[5];       // 1.6M
    float* out = (float*)d_out;

    const int npp  = (N + P - 1) / P;          // 12500 (< 2^14 for packing)
    const int NW   = (N + WN - 1) / WN;        // 800 windows
    const int cap1 = E / P + 16384;
    int cap2 = E / NW + 560;                   // 2560 = 10 regs * 256 thr
    if (cap2 > 2560) cap2 = 2560;              // k_sortwin register budget

    const unsigned long long M = ((1ull << 32) + npp - 1) / npp;

    // workspace: A | p2 | rowinfo | dinv | gcur1 | gcur2 ; p1 aliases A
    float* A       = (float*)d_ws;                     // N*FD
    int*   p2      = (int*)(A + (size_t)N * FD);       // NW*cap2
    int*   rowinfo = p2 + (size_t)NW * cap2;           // N
    float* dinv    = (float*)(rowinfo + N);            // N
    int*   gcur1   = (int*)(dinv + N);                 // P
    int*   gcur2   = gcur1 + P;                        // NW
    int*   p1      = (int*)A;                          // P*cap1

    k_init<<<1, 1024, 0, stream>>>(gcur1, cap1, gcur2, cap2, NW);
    k_part8<<<(E + 4095) / 4096, 256, 0, stream>>>(src, dst, E, M, npp, gcur1, cap1, p1);
    int nb2 = (cap1 + 4095) / 4096;
    k_partwin<<<P * nb2, 256, 0, stream>>>(p1, gcur1, cap1, npp, gcur2, cap2, p2);
    k_sortwin<<<NW, 256, 0, stream>>>(p2, gcur2, cap2, rowinfo, dinv, N);

    int gblocks = (N + 255) / 256;
    // layer 1: A' = dinv.*(emb @ W1); h = dinv.*(sum A'[col] + A'[self]) + b1
    k_gemm<128, false><<<gblocks, 256, 0, stream>>>(emb, W1, dinv, A, N);
    k_agg<<<(N * 16 + 255) / 256, 256, 0, stream>>>(A, p2, rowinfo, cap2, dinv, b1, out, N);
    // layer 2: A'' = dinv.*(relu(h) @ W2); out = dinv.*(sum + self) + b2
    k_gemm<64, true><<<gblocks, 256, 0, stream>>>(out, W2, dinv, A, N);
    k_agg<<<(N * 16 + 255) / 256, 256, 0, stream>>>(A, p2, rowinfo, cap2, dinv, b2, out, N);
}

// Round 8
// 263.830 us; speedup vs baseline: 5.5797x; 1.0374x over previous
//
#include <hip/hip_runtime.h>

// Problem constants: N=100000 nodes, E=1.6M edges, D=128, H=O=64.
constexpr int FD = 64;    // feature dim of both layers
constexpr int P  = 8;     // level-1 dst buckets (~XCDs)
constexpr int WN = 125;   // nodes per window (level-2)
constexpr int SRC_BITS = 17;                 // src id fits 17 bits (N <= 131072)
constexpr int SRC_MASK = (1 << SRC_BITS) - 1;
constexpr int G1S = 16;   // gcur1 stride (one counter per 64B line)

__device__ __forceinline__ int part_of(int d, unsigned long long M) {
    return (int)(((unsigned long long)(unsigned)d * M) >> 32);  // == d / npp
}

// ---------------- init per-call cursors -------------------------------------
__global__ void k_init(int* __restrict__ gcur1, int cap1,
                       int* __restrict__ gcur2, int cap2, int NW) {
    int i = threadIdx.x;
    if (i < P)  gcur1[i * G1S] = i * cap1;
    if (i < NW) gcur2[i] = i * cap2;
}

// ---------------- level 1: 8-way split by dst range, packed output -----------
// p1[pos] = ((d - bucket*npp) << 17) | s.  CH=1024 -> ~1563 blocks (occupancy).
__global__ __launch_bounds__(256) void k_part8(const int* __restrict__ src,
                                               const int* __restrict__ dst, int E,
                                               unsigned long long M, int npp,
                                               int* __restrict__ gcur1, int cap1,
                                               int* __restrict__ p1) {
    constexpr int CH = 1024;
    __shared__ int hh[P], bbase[P], lcur[P];
    if (threadIdx.x < P) hh[threadIdx.x] = 0;
    __syncthreads();
    const int e0 = blockIdx.x * CH;
    const int e1 = min(e0 + CH, E);
    const int lane = threadIdx.x & 63;
    for (int base = e0; base < e1; base += 256) {
        int e = base + threadIdx.x;
        bool valid = e < e1;
        int b = 0;
        if (valid) b = part_of(__builtin_nontemporal_load(&dst[e]), M);
#pragma unroll
        for (int q = 0; q < P; ++q) {
            unsigned long long m = __ballot(valid && b == q);
            if (m && lane == 0) atomicAdd(&hh[q], __popcll(m));
        }
    }
    __syncthreads();
    if (threadIdx.x < P) {
        bbase[threadIdx.x] = atomicAdd(&gcur1[threadIdx.x * G1S], hh[threadIdx.x]);
        lcur[threadIdx.x] = 0;
    }
    __syncthreads();
    for (int base = e0; base < e1; base += 256) {
        int e = base + threadIdx.x;
        bool valid = e < e1;
        int d = 0, s = 0, b = 0;
        if (valid) { d = dst[e]; s = src[e]; b = part_of(d, M); }
#pragma unroll
        for (int q = 0; q < P; ++q) {
            unsigned long long m = __ballot(valid && b == q);
            if (!m) continue;
            int leader = __ffsll((unsigned long long)m) - 1;
            int wbase = 0;
            if (lane == leader) wbase = atomicAdd(&lcur[q], __popcll(m));
            wbase = __shfl(wbase, leader, 64);
            if (valid && b == q) {
                int rank = __popcll(m & ((1ull << lane) - 1));
                int pos = bbase[q] + wbase + rank;
                if (pos < (q + 1) * cap1)
                    p1[pos] = ((d - q * npp) << SRC_BITS) | s;
            }
        }
    }
}

// ---------------- level 2: split bucket into 125-node windows ----------------
// p2[pos] = (window_local_dst << 17) | s.  CH=1024 -> ~1696 blocks.
__global__ __launch_bounds__(256) void k_partwin(const int* __restrict__ p1,
                                                 const int* __restrict__ gcur1, int cap1,
                                                 int npp, unsigned long long M2,
                                                 int* __restrict__ gcur2, int cap2,
                                                 int* __restrict__ p2) {
    constexpr int CH = 1024;
    constexpr int MAXW = 128;
    __shared__ int hh[MAXW], wbase[MAXW], lcur[MAXW];
    const int p   = blockIdx.x & (P - 1);
    const int j   = blockIdx.x >> 3;
    const int wlo = (p * npp) / WN;
    const int whi = ((p + 1) * npp - 1) / WN;
    const int nw  = whi - wlo + 1;             // <= 101
    for (int t = threadIdx.x; t < nw; t += 256) hh[t] = 0;
    __syncthreads();
    const int lo = p * cap1 + j * CH;
    const int hi = min(lo + CH, gcur1[p * G1S]);
    if (lo >= hi) return;
    for (int e = lo + threadIdx.x; e < hi; e += 256) {
        int pk = __builtin_nontemporal_load(&p1[e]);
        int d  = p * npp + (pk >> SRC_BITS);
        int w  = (int)(((unsigned long long)(unsigned)d * M2) >> 32);   // d/WN
        atomicAdd(&hh[w - wlo], 1);
    }
    __syncthreads();
    for (int t = threadIdx.x; t < nw; t += 256) {
        wbase[t] = hh[t] ? atomicAdd(&gcur2[wlo + t], hh[t]) : 0;
        lcur[t] = 0;
    }
    __syncthreads();
    for (int e = lo + threadIdx.x; e < hi; e += 256) {
        int pk = p1[e];
        int s  = pk & SRC_MASK;
        int d  = p * npp + (pk >> SRC_BITS);
        int w  = (int)(((unsigned long long)(unsigned)d * M2) >> 32);   // d/WN
        int hw = w - wlo;
        int pos = wbase[hw] + atomicAdd(&lcur[hw], 1);
        if (pos < (w + 1) * cap2)
            p2[pos] = ((d - w * WN) << SRC_BITS) | s;
    }
}

// ---------------- level 3: in-place counting sort per window -----------------
__global__ __launch_bounds__(256) void k_sortwin(int* __restrict__ p2,
                                                 const int* __restrict__ gcur2, int cap2,
                                                 int* __restrict__ rowinfo,
                                                 float* __restrict__ dinv, int N) {
    __shared__ int hist[WN], beg[WN], cur[WN];
    const int w  = blockIdx.x;
    const int lo = w * cap2;
    const int hi = min(gcur2[w], lo + cap2);
    const int cnt = hi - lo;
    for (int t = threadIdx.x; t < WN; t += 256) hist[t] = 0;
    __syncthreads();
    int pk[10];                      // cap2 <= 2560 = 10*256
#pragma unroll
    for (int j = 0; j < 10; ++j) {
        int i = j * 256 + threadIdx.x;
        pk[j] = (i < cnt) ? p2[lo + i] : -1;
        if (pk[j] >= 0) atomicAdd(&hist[pk[j] >> SRC_BITS], 1);
    }
    __syncthreads();
    if (threadIdx.x < 64) {          // wave 0: exclusive scan of hist[0..124]
        int lane = threadIdx.x;
        int v0 = hist[lane];
        int x0 = v0;
#pragma unroll
        for (int o = 1; o < 64; o <<= 1) { int y = __shfl_up(x0, o, 64); if (lane >= o) x0 += y; }
        int tot0 = __shfl(x0, 63, 64);
        int v1 = (lane < WN - 64) ? hist[64 + lane] : 0;
        int x1 = v1;
#pragma unroll
        for (int o = 1; o < 64; o <<= 1) { int y = __shfl_up(x1, o, 64); if (lane >= o) x1 += y; }
        int b0 = x0 - v0;
        beg[lane] = b0; cur[lane] = b0;
        if (lane < WN - 64) {
            int b1 = tot0 + x1 - v1;
            beg[64 + lane] = b1; cur[64 + lane] = b1;
        }
    }
    __syncthreads();
#pragma unroll
    for (int j = 0; j < 10; ++j) {
        if (pk[j] >= 0) {
            int ld  = pk[j] >> SRC_BITS;
            int pos = atomicAdd(&cur[ld], 1);
            p2[lo + pos] = pk[j] & SRC_MASK;   // sorted src id
        }
    }
    for (int t = threadIdx.x; t < WN; t += 256) {
        int node = w * WN + t;
        if (node < N) {
            rowinfo[node] = beg[t] | (hist[t] << 16);
            dinv[node] = rsqrtf((float)(hist[t] + 1));   // +1 self-loop
        }
    }
}

// ---------------- register-tiled GEMM: Y = dinv .* (act(X) @ W) --------------
template <int K, bool RELU>
__global__ __launch_bounds__(256) void k_gemm(const float* __restrict__ X,
                                              const float* __restrict__ W,
                                              const float* __restrict__ dinv,
                                              float* __restrict__ Y, int n) {
    constexpr int ASTR = 260;
    __shared__ __align__(16) float Bs[K * FD];
    __shared__ __align__(16) float As[32 * ASTR];
    for (int i = threadIdx.x; i < K * FD / 4; i += 256)
        ((float4*)Bs)[i] = ((const float4*)W)[i];

    const int rt   = threadIdx.x >> 3;
    const int ct   = threadIdx.x & 7;
    const int row0 = blockIdx.x * 256;
    float acc[8][8] = {};

    for (int kp = 0; kp < K; kp += 32) {
        __syncthreads();
        const int mq = threadIdx.x >> 3;
        const int q  = threadIdx.x & 7;
        float4 tv[8];
#pragma unroll
        for (int pass = 0; pass < 8; ++pass) {
            int grow = row0 + mq + pass * 32;
            float4 v = make_float4(0.f, 0.f, 0.f, 0.f);
            if (grow < n) {
                v = *(const float4*)&X[(size_t)grow * K + kp + q * 4];
                if (RELU) {
                    v.x = fmaxf(v.x, 0.f); v.y = fmaxf(v.y, 0.f);
                    v.z = fmaxf(v.z, 0.f); v.w = fmaxf(v.w, 0.f);
                }
            }
            tv[pass] = v;
        }
#pragma unroll
        for (int pass = 0; pass < 8; ++pass) {
            int m = mq + pass * 32;
            As[(q * 4 + 0) * ASTR + m] = tv[pass].x;
            As[(q * 4 + 1) * ASTR + m] = tv[pass].y;
            As[(q * 4 + 2) * ASTR + m] = tv[pass].z;
            As[(q * 4 + 3) * ASTR + m] = tv[pass].w;
        }
        __syncthreads();
#pragma unroll 8
        for (int k = 0; k < 32; ++k) {
            float4 a0 = *(const float4*)&As[k * ASTR + rt * 8];
            float4 a1 = *(const float4*)&As[k * ASTR + rt * 8 + 4];
            float4 b0 = *(const float4*)&Bs[(kp + k) * FD + ct * 8];
            float4 b1 = *(const float4*)&Bs[(kp + k) * FD + ct * 8 + 4];
            float af[8] = {a0.x, a0.y, a0.z, a0.w, a1.x, a1.y, a1.z, a1.w};
            float bf[8] = {b0.x, b0.y, b0.z, b0.w, b1.x, b1.y, b1.z, b1.w};
#pragma unroll
            for (int i = 0; i < 8; ++i)
#pragma unroll
                for (int j = 0; j < 8; ++j)
                    acc[i][j] = fmaf(af[i], bf[j], acc[i][j]);
        }
    }
#pragma unroll
    for (int i = 0; i < 8; ++i) {
        int r = row0 + rt * 8 + i;
        if (r < n) {
            float sc = dinv[r];
            float4 o0 = make_float4(acc[i][0] * sc, acc[i][1] * sc,
                                    acc[i][2] * sc, acc[i][3] * sc);
            float4 o1 = make_float4(acc[i][4] * sc, acc[i][5] * sc,
                                    acc[i][6] * sc, acc[i][7] * sc);
            *(float4*)&Y[(size_t)r * FD + ct * 8]     = o0;
            *(float4*)&Y[(size_t)r * FD + ct * 8 + 4] = o1;
        }
    }
}

// ---------------- edge aggregation (register accumulate, 8-deep MLP) ---------
// X pre-scaled by dinv:  out[d] = dinv[d]*(sum_{src in row d} X[src] + X[d]) + b
__global__ __launch_bounds__(256) void k_agg(const float* __restrict__ X,
                                             const int* __restrict__ col,
                                             const int* __restrict__ rowinfo, int cap2,
                                             const float* __restrict__ dinv,
                                             const float* __restrict__ bias,
                                             float* __restrict__ out, int n) {
    int t = blockIdx.x * 256 + threadIdx.x;
    int node = t >> 4;
    int lane = t & 15;
    if (node >= n) return;
    int info = rowinfo[node];
    int w    = (int)((unsigned)node / WN);
    int beg  = w * cap2 + (info & 0xFFFF);
    int end  = beg + (info >> 16);
    const float4* Xv = (const float4*)X;
    float4 sv = Xv[(size_t)node * 16 + lane];   // self term (issued early)
    float4 a0 = {0,0,0,0}, a1 = {0,0,0,0}, a2 = {0,0,0,0}, a3 = {0,0,0,0};
    int e = beg;
    for (; e + 8 <= end; e += 8) {
        int s0 = col[e],     s1 = col[e + 1], s2 = col[e + 2], s3 = col[e + 3];
        int s4 = col[e + 4], s5 = col[e + 5], s6 = col[e + 6], s7 = col[e + 7];
        float4 v0 = Xv[(size_t)s0 * 16 + lane];
        float4 v1 = Xv[(size_t)s1 * 16 + lane];
        float4 v2 = Xv[(size_t)s2 * 16 + lane];
        float4 v3 = Xv[(size_t)s3 * 16 + lane];
        float4 v4 = Xv[(size_t)s4 * 16 + lane];
        float4 v5 = Xv[(size_t)s5 * 16 + lane];
        float4 v6 = Xv[(size_t)s6 * 16 + lane];
        float4 v7 = Xv[(size_t)s7 * 16 + lane];
        a0.x += v0.x; a0.y += v0.y; a0.z += v0.z; a0.w += v0.w;
        a1.x += v1.x; a1.y += v1.y; a1.z += v1.z; a1.w += v1.w;
        a2.x += v2.x; a2.y += v2.y; a2.z += v2.z; a2.w += v2.w;
        a3.x += v3.x; a3.y += v3.y; a3.z += v3.z; a3.w += v3.w;
        a0.x += v4.x; a0.y += v4.y; a0.z += v4.z; a0.w += v4.w;
        a1.x += v5.x; a1.y += v5.y; a1.z += v5.z; a1.w += v5.w;
        a2.x += v6.x; a2.y += v6.y; a2.z += v6.z; a2.w += v6.w;
        a3.x += v7.x; a3.y += v7.y; a3.z += v7.z; a3.w += v7.w;
    }
    for (; e + 4 <= end; e += 4) {
        int s0 = col[e], s1 = col[e + 1], s2 = col[e + 2], s3 = col[e + 3];
        float4 v0 = Xv[(size_t)s0 * 16 + lane];
        float4 v1 = Xv[(size_t)s1 * 16 + lane];
        float4 v2 = Xv[(size_t)s2 * 16 + lane];
        float4 v3 = Xv[(size_t)s3 * 16 + lane];
        a0.x += v0.x; a0.y += v0.y; a0.z += v0.z; a0.w += v0.w;
        a1.x += v1.x; a1.y += v1.y; a1.z += v1.z; a1.w += v1.w;
        a2.x += v2.x; a2.y += v2.y; a2.z += v2.z; a2.w += v2.w;
        a3.x += v3.x; a3.y += v3.y; a3.z += v3.z; a3.w += v3.w;
    }
    for (; e < end; ++e) {
        float4 v = Xv[(size_t)col[e] * 16 + lane];
        a0.x += v.x; a0.y += v.y; a0.z += v.z; a0.w += v.w;
    }
    float sx = a0.x + a1.x + a2.x + a3.x + sv.x;
    float sy = a0.y + a1.y + a2.y + a3.y + sv.y;
    float sz = a0.z + a1.z + a2.z + a3.z + sv.z;
    float sw = a0.w + a1.w + a2.w + a3.w + sv.w;
    float di = dinv[node];
    float4 b = ((const float4*)bias)[lane];
    float4 o;
    o.x = fmaf(di, sx, b.x);
    o.y = fmaf(di, sy, b.y);
    o.z = fmaf(di, sz, b.z);
    o.w = fmaf(di, sw, b.w);
    ((float4*)(out + (size_t)node * FD))[lane] = o;
}

// ---------------- launch ----------------

extern "C" void kernel_launch(void* const* d_in, const int* in_sizes, int n_in,
                              void* d_out, int out_size, void* d_ws, size_t ws_size,
                              hipStream_t stream) {
    const float* emb = (const float*)d_in[0];
    const float* W1  = (const float*)d_in[1];
    const float* b1  = (const float*)d_in[2];
    const float* W2  = (const float*)d_in[3];
    const float* b2  = (const float*)d_in[4];
    const int*   src = (const int*)d_in[5];
    const int*   dst = (const int*)d_in[6];

    const int D = 128;
    const int N = in_sizes[0] / D;   // 100000
    const int E = in_sizes[5];       // 1.6M
    float* out = (float*)d_out;

    const int npp  = (N + P - 1) / P;          // 12500 (< 2^14 for packing)
    const int NW   = (N + WN - 1) / WN;        // 800 windows
    const int cap1 = E / P + 16384;
    int cap2 = E / NW + 560;                   // 2560 = 10 regs * 256 thr
    if (cap2 > 2560) cap2 = 2560;              // k_sortwin register budget

    const unsigned long long M  = ((1ull << 32) + npp - 1) / npp;  // /npp
    const unsigned long long M2 = ((1ull << 32) + WN - 1) / WN;    // /125 (exact, d<2^17)

    // workspace: A | p2 | rowinfo | dinv | gcur1 | gcur2 ; p1 aliases A
    float* A       = (float*)d_ws;                     // N*FD
    int*   p2      = (int*)(A + (size_t)N * FD);       // NW*cap2
    int*   rowinfo = p2 + (size_t)NW * cap2;           // N
    float* dinv    = (float*)(rowinfo + N);            // N
    int*   gcur1   = (int*)(dinv + N);                 // P*G1S
    int*   gcur2   = gcur1 + P * G1S;                  // NW
    int*   p1      = (int*)A;                          // P*cap1

    k_init<<<1, 1024, 0, stream>>>(gcur1, cap1, gcur2, cap2, NW);
    k_part8<<<(E + 1023) / 1024, 256, 0, stream>>>(src, dst, E, M, npp, gcur1, cap1, p1);
    int nb2 = (cap1 + 1023) / 1024;
    k_partwin<<<P * nb2, 256, 0, stream>>>(p1, gcur1, cap1, npp, M2, gcur2, cap2, p2);
    k_sortwin<<<NW, 256, 0, stream>>>(p2, gcur2, cap2, rowinfo, dinv, N);

    int gblocks = (N + 255) / 256;
    // layer 1: A' = dinv.*(emb @ W1); h = dinv.*(sum A'[col] + A'[self]) + b1
    k_gemm<128, false><<<gblocks, 256, 0, stream>>>(emb, W1, dinv, A, N);
    k_agg<<<(N * 16 + 255) / 256, 256, 0, stream>>>(A, p2, rowinfo, cap2, dinv, b1, out, N);
    // layer 2: A'' = dinv.*(relu(h) @ W2); out = dinv.*(sum + self) + b2
    k_gemm<64, true><<<gblocks, 256, 0, stream>>>(out, W2, dinv, A, N);
    k_agg<<<(N * 16 + 255) / 256, 256, 0, stream>>>(A, p2, rowinfo, cap2, dinv, b2, out, N);
}

// Round 9
// 212.648 us; speedup vs baseline: 6.9227x; 1.2407x over previous
//
#include <hip/hip_runtime.h>

// Problem constants: N=100000 nodes, E=1.6M edges, D=128, H=O=64.
constexpr int FD = 64;    // feature dim of both layers
constexpr int P  = 8;     // level-1 dst buckets (~XCDs)
constexpr int WN = 125;   // nodes per window (level-2)
constexpr int SRC_BITS = 17;                 // src id fits 17 bits (N <= 131072)
constexpr int SRC_MASK = (1 << SRC_BITS) - 1;
constexpr int G1S = 16;   // gcur1 stride (one counter per 64B line)

__device__ __forceinline__ int part_of(int d, unsigned long long M) {
    return (int)(((unsigned long long)(unsigned)d * M) >> 32);  // == d / npp
}

// pack two f32 -> two bf16 (round-to-nearest-even) in one uint
__device__ __forceinline__ unsigned bf16pack(float a, float b) {
    unsigned ua = __float_as_uint(a), ub = __float_as_uint(b);
    ua = (ua + 0x7FFFu + ((ua >> 16) & 1u)) >> 16;
    ub = (ub + 0x7FFFu + ((ub >> 16) & 1u)) >> 16;
    return ua | (ub << 16);
}
// unpack 4 bf16 (uint2) -> float4
__device__ __forceinline__ float4 bf16x4(uint2 u) {
    float4 v;
    v.x = __uint_as_float(u.x << 16);
    v.y = __uint_as_float(u.x & 0xFFFF0000u);
    v.z = __uint_as_float(u.y << 16);
    v.w = __uint_as_float(u.y & 0xFFFF0000u);
    return v;
}

// ---------------- init per-call cursors -------------------------------------
__global__ void k_init(int* __restrict__ gcur1, int cap1,
                       int* __restrict__ gcur2, int cap2, int NW) {
    int i = threadIdx.x;
    if (i < P)  gcur1[i * G1S] = i * cap1;
    if (i < NW) gcur2[i] = i * cap2;
}

// ---------------- level 1: 8-way split by dst range, packed output -----------
__global__ __launch_bounds__(256) void k_part8(const int* __restrict__ src,
                                               const int* __restrict__ dst, int E,
                                               unsigned long long M, int npp,
                                               int* __restrict__ gcur1, int cap1,
                                               int* __restrict__ p1) {
    constexpr int CH = 1024;
    __shared__ int hh[P], bbase[P], lcur[P];
    if (threadIdx.x < P) hh[threadIdx.x] = 0;
    __syncthreads();
    const int e0 = blockIdx.x * CH;
    const int e1 = min(e0 + CH, E);
    const int lane = threadIdx.x & 63;
    for (int base = e0; base < e1; base += 256) {
        int e = base + threadIdx.x;
        bool valid = e < e1;
        int b = 0;
        if (valid) b = part_of(__builtin_nontemporal_load(&dst[e]), M);
#pragma unroll
        for (int q = 0; q < P; ++q) {
            unsigned long long m = __ballot(valid && b == q);
            if (m && lane == 0) atomicAdd(&hh[q], __popcll(m));
        }
    }
    __syncthreads();
    if (threadIdx.x < P) {
        bbase[threadIdx.x] = atomicAdd(&gcur1[threadIdx.x * G1S], hh[threadIdx.x]);
        lcur[threadIdx.x] = 0;
    }
    __syncthreads();
    for (int base = e0; base < e1; base += 256) {
        int e = base + threadIdx.x;
        bool valid = e < e1;
        int d = 0, s = 0, b = 0;
        if (valid) { d = dst[e]; s = src[e]; b = part_of(d, M); }
#pragma unroll
        for (int q = 0; q < P; ++q) {
            unsigned long long m = __ballot(valid && b == q);
            if (!m) continue;
            int leader = __ffsll((unsigned long long)m) - 1;
            int wbase = 0;
            if (lane == leader) wbase = atomicAdd(&lcur[q], __popcll(m));
            wbase = __shfl(wbase, leader, 64);
            if (valid && b == q) {
                int rank = __popcll(m & ((1ull << lane) - 1));
                int pos = bbase[q] + wbase + rank;
                if (pos < (q + 1) * cap1)
                    p1[pos] = ((d - q * npp) << SRC_BITS) | s;
            }
        }
    }
}

// ---------------- level 2: split bucket into 125-node windows ----------------
__global__ __launch_bounds__(256) void k_partwin(const int* __restrict__ p1,
                                                 const int* __restrict__ gcur1, int cap1,
                                                 int npp, unsigned long long M2,
                                                 int* __restrict__ gcur2, int cap2,
                                                 int* __restrict__ p2) {
    constexpr int CH = 1024;
    constexpr int MAXW = 128;
    __shared__ int hh[MAXW], wbase[MAXW], lcur[MAXW];
    const int p   = blockIdx.x & (P - 1);
    const int j   = blockIdx.x >> 3;
    const int wlo = (p * npp) / WN;
    const int whi = ((p + 1) * npp - 1) / WN;
    const int nw  = whi - wlo + 1;             // <= 101
    for (int t = threadIdx.x; t < nw; t += 256) hh[t] = 0;
    __syncthreads();
    const int lo = p * cap1 + j * CH;
    const int hi = min(lo + CH, gcur1[p * G1S]);
    if (lo >= hi) return;
    for (int e = lo + threadIdx.x; e < hi; e += 256) {
        int pk = __builtin_nontemporal_load(&p1[e]);
        int d  = p * npp + (pk >> SRC_BITS);
        int w  = (int)(((unsigned long long)(unsigned)d * M2) >> 32);   // d/WN
        atomicAdd(&hh[w - wlo], 1);
    }
    __syncthreads();
    for (int t = threadIdx.x; t < nw; t += 256) {
        wbase[t] = hh[t] ? atomicAdd(&gcur2[wlo + t], hh[t]) : 0;
        lcur[t] = 0;
    }
    __syncthreads();
    for (int e = lo + threadIdx.x; e < hi; e += 256) {
        int pk = p1[e];
        int s  = pk & SRC_MASK;
        int d  = p * npp + (pk >> SRC_BITS);
        int w  = (int)(((unsigned long long)(unsigned)d * M2) >> 32);   // d/WN
        int hw = w - wlo;
        int pos = wbase[hw] + atomicAdd(&lcur[hw], 1);
        if (pos < (w + 1) * cap2)
            p2[pos] = ((d - w * WN) << SRC_BITS) | s;
    }
}

// ---------------- level 3: in-place counting sort per window -----------------
__global__ __launch_bounds__(256) void k_sortwin(int* __restrict__ p2,
                                                 const int* __restrict__ gcur2, int cap2,
                                                 int* __restrict__ rowinfo,
                                                 float* __restrict__ dinv, int N) {
    __shared__ int hist[WN], beg[WN], cur[WN];
    const int w  = blockIdx.x;
    const int lo = w * cap2;
    const int hi = min(gcur2[w], lo + cap2);
    const int cnt = hi - lo;
    for (int t = threadIdx.x; t < WN; t += 256) hist[t] = 0;
    __syncthreads();
    int pk[10];                      // cap2 <= 2560 = 10*256
#pragma unroll
    for (int j = 0; j < 10; ++j) {
        int i = j * 256 + threadIdx.x;
        pk[j] = (i < cnt) ? p2[lo + i] : -1;
        if (pk[j] >= 0) atomicAdd(&hist[pk[j] >> SRC_BITS], 1);
    }
    __syncthreads();
    if (threadIdx.x < 64) {          // wave 0: exclusive scan of hist[0..124]
        int lane = threadIdx.x;
        int v0 = hist[lane];
        int x0 = v0;
#pragma unroll
        for (int o = 1; o < 64; o <<= 1) { int y = __shfl_up(x0, o, 64); if (lane >= o) x0 += y; }
        int tot0 = __shfl(x0, 63, 64);
        int v1 = (lane < WN - 64) ? hist[64 + lane] : 0;
        int x1 = v1;
#pragma unroll
        for (int o = 1; o < 64; o <<= 1) { int y = __shfl_up(x1, o, 64); if (lane >= o) x1 += y; }
        int b0 = x0 - v0;
        beg[lane] = b0; cur[lane] = b0;
        if (lane < WN - 64) {
            int b1 = tot0 + x1 - v1;
            beg[64 + lane] = b1; cur[64 + lane] = b1;
        }
    }
    __syncthreads();
#pragma unroll
    for (int j = 0; j < 10; ++j) {
        if (pk[j] >= 0) {
            int ld  = pk[j] >> SRC_BITS;
            int pos = atomicAdd(&cur[ld], 1);
            p2[lo + pos] = pk[j] & SRC_MASK;   // sorted src id
        }
    }
    for (int t = threadIdx.x; t < WN; t += 256) {
        int node = w * WN + t;
        if (node < N) {
            rowinfo[node] = beg[t] | (hist[t] << 16);
            dinv[node] = rsqrtf((float)(hist[t] + 1));   // +1 self-loop
        }
    }
}

// ---------------- register-tiled GEMM: Yb = bf16( dinv .* (act(X) @ W) ) -----
// Yb rows are 64 bf16 = 128B (gather operand for k_agg).
template <int K, bool RELU>
__global__ __launch_bounds__(256) void k_gemm(const float* __restrict__ X,
                                              const float* __restrict__ W,
                                              const float* __restrict__ dinv,
                                              unsigned* __restrict__ Yb, int n) {
    constexpr int ASTR = 260;
    __shared__ __align__(16) float Bs[K * FD];
    __shared__ __align__(16) float As[32 * ASTR];
    for (int i = threadIdx.x; i < K * FD / 4; i += 256)
        ((float4*)Bs)[i] = ((const float4*)W)[i];

    const int rt   = threadIdx.x >> 3;
    const int ct   = threadIdx.x & 7;
    const int row0 = blockIdx.x * 256;
    float acc[8][8] = {};

    for (int kp = 0; kp < K; kp += 32) {
        __syncthreads();
        const int mq = threadIdx.x >> 3;
        const int q  = threadIdx.x & 7;
        float4 tv[8];
#pragma unroll
        for (int pass = 0; pass < 8; ++pass) {
            int grow = row0 + mq + pass * 32;
            float4 v = make_float4(0.f, 0.f, 0.f, 0.f);
            if (grow < n) {
                v = *(const float4*)&X[(size_t)grow * K + kp + q * 4];
                if (RELU) {
                    v.x = fmaxf(v.x, 0.f); v.y = fmaxf(v.y, 0.f);
                    v.z = fmaxf(v.z, 0.f); v.w = fmaxf(v.w, 0.f);
                }
            }
            tv[pass] = v;
        }
#pragma unroll
        for (int pass = 0; pass < 8; ++pass) {
            int m = mq + pass * 32;
            As[(q * 4 + 0) * ASTR + m] = tv[pass].x;
            As[(q * 4 + 1) * ASTR + m] = tv[pass].y;
            As[(q * 4 + 2) * ASTR + m] = tv[pass].z;
            As[(q * 4 + 3) * ASTR + m] = tv[pass].w;
        }
        __syncthreads();
#pragma unroll 8
        for (int k = 0; k < 32; ++k) {
            float4 a0 = *(const float4*)&As[k * ASTR + rt * 8];
            float4 a1 = *(const float4*)&As[k * ASTR + rt * 8 + 4];
            float4 b0 = *(const float4*)&Bs[(kp + k) * FD + ct * 8];
            float4 b1 = *(const float4*)&Bs[(kp + k) * FD + ct * 8 + 4];
            float af[8] = {a0.x, a0.y, a0.z, a0.w, a1.x, a1.y, a1.z, a1.w};
            float bf[8] = {b0.x, b0.y, b0.z, b0.w, b1.x, b1.y, b1.z, b1.w};
#pragma unroll
            for (int i = 0; i < 8; ++i)
#pragma unroll
                for (int j = 0; j < 8; ++j)
                    acc[i][j] = fmaf(af[i], bf[j], acc[i][j]);
        }
    }
#pragma unroll
    for (int i = 0; i < 8; ++i) {
        int r = row0 + rt * 8 + i;
        if (r < n) {
            float sc = dinv[r];
            uint4 w;
            w.x = bf16pack(acc[i][0] * sc, acc[i][1] * sc);
            w.y = bf16pack(acc[i][2] * sc, acc[i][3] * sc);
            w.z = bf16pack(acc[i][4] * sc, acc[i][5] * sc);
            w.w = bf16pack(acc[i][6] * sc, acc[i][7] * sc);
            ((uint4*)Yb)[(size_t)r * 8 + ct] = w;   // row = 8 uint4 (128B)
        }
    }
}

// ---------------- edge aggregation (bf16 gather, f32 accumulate) -------------
// Xb rows = 64 bf16 (pre-scaled by dinv[src]).
// out[d] = dinv[d]*(sum_{src in row d} Xb[src] + Xb[d]) + bias   (f32 out)
__global__ __launch_bounds__(256) void k_agg(const unsigned* __restrict__ Xb,
                                             const int* __restrict__ col,
                                             const int* __restrict__ rowinfo, int cap2,
                                             const float* __restrict__ dinv,
                                             const float* __restrict__ bias,
                                             float* __restrict__ out, int n) {
    int t = blockIdx.x * 256 + threadIdx.x;
    int node = t >> 4;
    int lane = t & 15;
    if (node >= n) return;
    int info = rowinfo[node];
    int w    = (int)((unsigned)node / WN);
    int beg  = w * cap2 + (info & 0xFFFF);
    int end  = beg + (info >> 16);
    const uint2* Xv = (const uint2*)Xb;   // 16 uint2 (8B) per row
    uint2 svu = Xv[(size_t)node * 16 + lane];       // self term (early)
    float4 a0 = {0,0,0,0}, a1 = {0,0,0,0}, a2 = {0,0,0,0}, a3 = {0,0,0,0};
    int e = beg;
    for (; e + 8 <= end; e += 8) {
        int s0 = col[e],     s1 = col[e + 1], s2 = col[e + 2], s3 = col[e + 3];
        int s4 = col[e + 4], s5 = col[e + 5], s6 = col[e + 6], s7 = col[e + 7];
        uint2 u0 = Xv[(size_t)s0 * 16 + lane];
        uint2 u1 = Xv[(size_t)s1 * 16 + lane];
        uint2 u2 = Xv[(size_t)s2 * 16 + lane];
        uint2 u3 = Xv[(size_t)s3 * 16 + lane];
        uint2 u4 = Xv[(size_t)s4 * 16 + lane];
        uint2 u5 = Xv[(size_t)s5 * 16 + lane];
        uint2 u6 = Xv[(size_t)s6 * 16 + lane];
        uint2 u7 = Xv[(size_t)s7 * 16 + lane];
        float4 v0 = bf16x4(u0), v1 = bf16x4(u1), v2 = bf16x4(u2), v3 = bf16x4(u3);
        float4 v4 = bf16x4(u4), v5 = bf16x4(u5), v6 = bf16x4(u6), v7 = bf16x4(u7);
        a0.x += v0.x; a0.y += v0.y; a0.z += v0.z; a0.w += v0.w;
        a1.x += v1.x; a1.y += v1.y; a1.z += v1.z; a1.w += v1.w;
        a2.x += v2.x; a2.y += v2.y; a2.z += v2.z; a2.w += v2.w;
        a3.x += v3.x; a3.y += v3.y; a3.z += v3.z; a3.w += v3.w;
        a0.x += v4.x; a0.y += v4.y; a0.z += v4.z; a0.w += v4.w;
        a1.x += v5.x; a1.y += v5.y; a1.z += v5.z; a1.w += v5.w;
        a2.x += v6.x; a2.y += v6.y; a2.z += v6.z; a2.w += v6.w;
        a3.x += v7.x; a3.y += v7.y; a3.z += v7.z; a3.w += v7.w;
    }
    for (; e + 4 <= end; e += 4) {
        int s0 = col[e], s1 = col[e + 1], s2 = col[e + 2], s3 = col[e + 3];
        uint2 u0 = Xv[(size_t)s0 * 16 + lane];
        uint2 u1 = Xv[(size_t)s1 * 16 + lane];
        uint2 u2 = Xv[(size_t)s2 * 16 + lane];
        uint2 u3 = Xv[(size_t)s3 * 16 + lane];
        float4 v0 = bf16x4(u0), v1 = bf16x4(u1), v2 = bf16x4(u2), v3 = bf16x4(u3);
        a0.x += v0.x; a0.y += v0.y; a0.z += v0.z; a0.w += v0.w;
        a1.x += v1.x; a1.y += v1.y; a1.z += v1.z; a1.w += v1.w;
        a2.x += v2.x; a2.y += v2.y; a2.z += v2.z; a2.w += v2.w;
        a3.x += v3.x; a3.y += v3.y; a3.z += v3.z; a3.w += v3.w;
    }
    for (; e < end; ++e) {
        float4 v = bf16x4(Xv[(size_t)col[e] * 16 + lane]);
        a0.x += v.x; a0.y += v.y; a0.z += v.z; a0.w += v.w;
    }
    float4 sv = bf16x4(svu);
    float sx = a0.x + a1.x + a2.x + a3.x + sv.x;
    float sy = a0.y + a1.y + a2.y + a3.y + sv.y;
    float sz = a0.z + a1.z + a2.z + a3.z + sv.z;
    float sw = a0.w + a1.w + a2.w + a3.w + sv.w;
    float di = dinv[node];
    float4 b = ((const float4*)bias)[lane];
    float4 o;
    o.x = fmaf(di, sx, b.x);
    o.y = fmaf(di, sy, b.y);
    o.z = fmaf(di, sz, b.z);
    o.w = fmaf(di, sw, b.w);
    ((float4*)(out + (size_t)node * FD))[lane] = o;
}

// ---------------- launch ----------------

extern "C" void kernel_launch(void* const* d_in, const int* in_sizes, int n_in,
                              void* d_out, int out_size, void* d_ws, size_t ws_size,
                              hipStream_t stream) {
    const float* emb = (const float*)d_in[0];
    const float* W1  = (const float*)d_in[1];
    const float* b1  = (const float*)d_in[2];
    const float* W2  = (const float*)d_in[3];
    const float* b2  = (const float*)d_in[4];
    const int*   src = (const int*)d_in[5];
    const int*   dst = (const int*)d_in[6];

    const int D = 128;
    const int N = in_sizes[0] / D;   // 100000
    const int E = in_sizes[5];       // 1.6M
    float* out = (float*)d_out;

    const int npp  = (N + P - 1) / P;          // 12500 (< 2^14 for packing)
    const int NW   = (N + WN - 1) / WN;        // 800 windows
    const int cap1 = E / P + 16384;
    int cap2 = E / NW + 560;                   // 2560 = 10 regs * 256 thr
    if (cap2 > 2560) cap2 = 2560;              // k_sortwin register budget

    const unsigned long long M  = ((1ull << 32) + npp - 1) / npp;  // /npp
    const unsigned long long M2 = ((1ull << 32) + WN - 1) / WN;    // /125 (exact, d<2^17)

    // workspace (4B units): Ab(bf16 table) | p2 | rowinfo | dinv | gcur1 | gcur2 | p1
    unsigned* Ab     = (unsigned*)d_ws;                 // N*32 uints (rows of 64 bf16)
    int*   p2      = (int*)(Ab + (size_t)N * 32);       // NW*cap2
    int*   rowinfo = p2 + (size_t)NW * cap2;            // N
    float* dinv    = (float*)(rowinfo + N);             // N
    int*   gcur1   = (int*)(dinv + N);                  // P*G1S
    int*   gcur2   = gcur1 + P * G1S;                   // NW
    int*   p1      = gcur2 + NW;                        // P*cap1

    k_init<<<1, 1024, 0, stream>>>(gcur1, cap1, gcur2, cap2, NW);
    k_part8<<<(E + 1023) / 1024, 256, 0, stream>>>(src, dst, E, M, npp, gcur1, cap1, p1);
    int nb2 = (cap1 + 1023) / 1024;
    k_partwin<<<P * nb2, 256, 0, stream>>>(p1, gcur1, cap1, npp, M2, gcur2, cap2, p2);
    k_sortwin<<<NW, 256, 0, stream>>>(p2, gcur2, cap2, rowinfo, dinv, N);

    int gblocks = (N + 255) / 256;
    // layer 1: Ab = bf16(dinv.*(emb @ W1)); h = dinv.*(sum Ab[col] + Ab[self]) + b1
    k_gemm<128, false><<<gblocks, 256, 0, stream>>>(emb, W1, dinv, Ab, N);
    k_agg<<<(N * 16 + 255) / 256, 256, 0, stream>>>(Ab, p2, rowinfo, cap2, dinv, b1, out, N);
    // layer 2: Ab = bf16(dinv.*(relu(h) @ W2)); out = dinv.*(sum + self) + b2
    k_gemm<64, true><<<gblocks, 256, 0, stream>>>(out, W2, dinv, Ab, N);
    k_agg<<<(N * 16 + 255) / 256, 256, 0, stream>>>(Ab, p2, rowinfo, cap2, dinv, b2, out, N);
}

// Round 10
// 199.782 us; speedup vs baseline: 7.3685x; 1.0644x over previous
//
#include <hip/hip_runtime.h>

// Problem constants: N=100000 nodes, E=1.6M edges, D=128, H=O=64.
constexpr int FD = 64;    // feature dim of both layers
constexpr int P  = 8;     // level-1 dst buckets (~XCDs)
constexpr int WN = 125;   // nodes per window (level-2)
constexpr int SRC_BITS = 17;                 // src id fits 17 bits (N <= 131072)
constexpr int SRC_MASK = (1 << SRC_BITS) - 1;
constexpr int G1S = 16;   // gcur1 stride (one counter per 64B line)

__device__ __forceinline__ int part_of(int d, unsigned long long M) {
    return (int)(((unsigned long long)(unsigned)d * M) >> 32);  // == d / npp
}

// pack two f32 -> two bf16 (round-to-nearest-even) in one uint
__device__ __forceinline__ unsigned bf16pack(float a, float b) {
    unsigned ua = __float_as_uint(a), ub = __float_as_uint(b);
    ua = (ua + 0x7FFFu + ((ua >> 16) & 1u)) >> 16;
    ub = (ub + 0x7FFFu + ((ub >> 16) & 1u)) >> 16;
    return ua | (ub << 16);
}
// unpack 4 bf16 (uint2) -> float4
__device__ __forceinline__ float4 bf16x4(uint2 u) {
    float4 v;
    v.x = __uint_as_float(u.x << 16);
    v.y = __uint_as_float(u.x & 0xFFFF0000u);
    v.z = __uint_as_float(u.y << 16);
    v.w = __uint_as_float(u.y & 0xFFFF0000u);
    return v;
}

// ---------------- init per-call cursors -------------------------------------
__global__ void k_init(int* __restrict__ gcur1, int cap1,
                       int* __restrict__ gcur2, int cap2, int NW) {
    int i = threadIdx.x;
    if (i < P)  gcur1[i * G1S] = i * cap1;
    if (i < NW) gcur2[i] = i * cap2;
}

// ---------------- level 1: 8-way split, 3-ballot multisplit, single pass -----
// Stages 4 edges/thread in registers; rank/count via bitwise ballot intersection
// (3 ballots per 64-edge batch instead of an 8-iteration ballot loop).
__global__ __launch_bounds__(256) void k_part8(const int* __restrict__ src,
                                               const int* __restrict__ dst, int E,
                                               unsigned long long M, int npp,
                                               int* __restrict__ gcur1, int cap1,
                                               int* __restrict__ p1) {
    constexpr int CH = 1024;
    __shared__ int hh[P], bbase[P], lcur[P];
    if (threadIdx.x < P) hh[threadIdx.x] = 0;
    __syncthreads();
    const int e0  = blockIdx.x * CH;
    const int rem = min(CH, E - e0);
    const int lane = threadIdx.x & 63;
    const unsigned long long lmlt = (lane == 63) ? ~0ull >> 1 : (1ull << lane) - 1;

    int dv[4], sv[4], bv[4], ldr[4], rnk[4], cnt[4];
    bool val[4];
    unsigned long long mm[4];
#pragma unroll
    for (int j = 0; j < 4; ++j) {
        int i = j * 256 + threadIdx.x;
        val[j] = i < rem;
        int e = e0 + (val[j] ? i : 0);
        dv[j] = __builtin_nontemporal_load(&dst[e]);
        sv[j] = __builtin_nontemporal_load(&src[e]);
        bv[j] = part_of(dv[j], M);
    }
#pragma unroll
    for (int j = 0; j < 4; ++j) {
        unsigned long long m0 = __ballot(val[j] && (bv[j] & 1));
        unsigned long long m1 = __ballot(val[j] && (bv[j] & 2));
        unsigned long long m2 = __ballot(val[j] && (bv[j] & 4));
        unsigned long long mv = __ballot(val[j]);
        unsigned long long t = ((bv[j] & 1) ? m0 : ~m0)
                             & ((bv[j] & 2) ? m1 : ~m1)
                             & ((bv[j] & 4) ? m2 : ~m2) & mv;
        mm[j]  = t;
        ldr[j] = __ffsll((unsigned long long)t) - 1;
        rnk[j] = __popcll(t & lmlt);
        cnt[j] = __popcll(t);
        if (val[j] && lane == ldr[j]) atomicAdd(&hh[bv[j]], cnt[j]);
    }
    __syncthreads();
    if (threadIdx.x < P) {
        bbase[threadIdx.x] = atomicAdd(&gcur1[threadIdx.x * G1S], hh[threadIdx.x]);
        lcur[threadIdx.x] = 0;
    }
    __syncthreads();
#pragma unroll
    for (int j = 0; j < 4; ++j) {
        int wb = 0;
        if (val[j] && lane == ldr[j]) wb = atomicAdd(&lcur[bv[j]], cnt[j]);
        wb = __shfl(wb, ldr[j] < 0 ? 0 : ldr[j], 64);   // group-leader broadcast
        if (val[j]) {
            int pos = bbase[bv[j]] + wb + rnk[j];
            if (pos < (bv[j] + 1) * cap1)
                p1[pos] = ((dv[j] - bv[j] * npp) << SRC_BITS) | sv[j];
        }
    }
}

// ---------------- level 2: split bucket into 125-node windows ----------------
// Register-staged pk (one global read); per-thread LDS atomics (101 counters,
// low contention; leader aggregation degenerates at groups<1 lane).
__global__ __launch_bounds__(256) void k_partwin(const int* __restrict__ p1,
                                                 const int* __restrict__ gcur1, int cap1,
                                                 int npp, unsigned long long M2,
                                                 int* __restrict__ gcur2, int cap2,
                                                 int* __restrict__ p2) {
    constexpr int CH = 1024;
    constexpr int MAXW = 128;
    __shared__ int hh[MAXW], wbase[MAXW], lcur[MAXW];
    const int p   = blockIdx.x & (P - 1);
    const int j   = blockIdx.x >> 3;
    const int wlo = (p * npp) / WN;
    const int whi = ((p + 1) * npp - 1) / WN;
    const int nw  = whi - wlo + 1;             // <= 101
    const int lo = p * cap1 + j * CH;
    const int hi = min(lo + CH, gcur1[p * G1S]);
    if (lo >= hi) return;                       // block-uniform
    for (int t = threadIdx.x; t < nw; t += 256) hh[t] = 0;
    __syncthreads();
    int pk[4], wv[4];
    bool val[4];
#pragma unroll
    for (int q = 0; q < 4; ++q) {
        int e = lo + q * 256 + threadIdx.x;
        val[q] = e < hi;
        pk[q] = val[q] ? __builtin_nontemporal_load(&p1[e]) : 0;
        int d = p * npp + (pk[q] >> SRC_BITS);
        wv[q] = (int)(((unsigned long long)(unsigned)d * M2) >> 32);   // d/WN
        if (val[q]) atomicAdd(&hh[wv[q] - wlo], 1);
    }
    __syncthreads();
    for (int t = threadIdx.x; t < nw; t += 256) {
        wbase[t] = hh[t] ? atomicAdd(&gcur2[wlo + t], hh[t]) : 0;
        lcur[t] = 0;
    }
    __syncthreads();
#pragma unroll
    for (int q = 0; q < 4; ++q) {
        if (val[q]) {
            int w  = wv[q];
            int hw = w - wlo;
            int d  = p * npp + (pk[q] >> SRC_BITS);
            int pos = wbase[hw] + atomicAdd(&lcur[hw], 1);
            if (pos < (w + 1) * cap2)
                p2[pos] = ((d - w * WN) << SRC_BITS) | (pk[q] & SRC_MASK);
        }
    }
}

// ---------------- level 3: in-place counting sort per window -----------------
__global__ __launch_bounds__(256) void k_sortwin(int* __restrict__ p2,
                                                 const int* __restrict__ gcur2, int cap2,
                                                 int* __restrict__ rowinfo,
                                                 float* __restrict__ dinv, int N) {
    __shared__ int hist[WN], beg[WN], cur[WN];
    const int w  = blockIdx.x;
    const int lo = w * cap2;
    const int hi = min(gcur2[w], lo + cap2);
    const int cnt = hi - lo;
    for (int t = threadIdx.x; t < WN; t += 256) hist[t] = 0;
    __syncthreads();
    int pk[10];                      // cap2 <= 2560 = 10*256
#pragma unroll
    for (int j = 0; j < 10; ++j) {
        int i = j * 256 + threadIdx.x;
        pk[j] = (i < cnt) ? p2[lo + i] : -1;
        if (pk[j] >= 0) atomicAdd(&hist[pk[j] >> SRC_BITS], 1);
    }
    __syncthreads();
    if (threadIdx.x < 64) {          // wave 0: exclusive scan of hist[0..124]
        int lane = threadIdx.x;
        int v0 = hist[lane];
        int x0 = v0;
#pragma unroll
        for (int o = 1; o < 64; o <<= 1) { int y = __shfl_up(x0, o, 64); if (lane >= o) x0 += y; }
        int tot0 = __shfl(x0, 63, 64);
        int v1 = (lane < WN - 64) ? hist[64 + lane] : 0;
        int x1 = v1;
#pragma unroll
        for (int o = 1; o < 64; o <<= 1) { int y = __shfl_up(x1, o, 64); if (lane >= o) x1 += y; }
        int b0 = x0 - v0;
        beg[lane] = b0; cur[lane] = b0;
        if (lane < WN - 64) {
            int b1 = tot0 + x1 - v1;
            beg[64 + lane] = b1; cur[64 + lane] = b1;
        }
    }
    __syncthreads();
#pragma unroll
    for (int j = 0; j < 10; ++j) {
        if (pk[j] >= 0) {
            int ld  = pk[j] >> SRC_BITS;
            int pos = atomicAdd(&cur[ld], 1);
            p2[lo + pos] = pk[j] & SRC_MASK;   // sorted src id
        }
    }
    for (int t = threadIdx.x; t < WN; t += 256) {
        int node = w * WN + t;
        if (node < N) {
            rowinfo[node] = beg[t] | (hist[t] << 16);
            dinv[node] = rsqrtf((float)(hist[t] + 1));   // +1 self-loop
        }
    }
}

// ---------------- register-tiled GEMM: Yb = bf16( dinv .* (act(X) @ W) ) -----
template <int K, bool RELU>
__global__ __launch_bounds__(256) void k_gemm(const float* __restrict__ X,
                                              const float* __restrict__ W,
                                              const float* __restrict__ dinv,
                                              unsigned* __restrict__ Yb, int n) {
    constexpr int ASTR = 260;
    __shared__ __align__(16) float Bs[K * FD];
    __shared__ __align__(16) float As[32 * ASTR];
    for (int i = threadIdx.x; i < K * FD / 4; i += 256)
        ((float4*)Bs)[i] = ((const float4*)W)[i];

    const int rt   = threadIdx.x >> 3;
    const int ct   = threadIdx.x & 7;
    const int row0 = blockIdx.x * 256;
    float acc[8][8] = {};

    for (int kp = 0; kp < K; kp += 32) {
        __syncthreads();
        const int mq = threadIdx.x >> 3;
        const int q  = threadIdx.x & 7;
        float4 tv[8];
#pragma unroll
        for (int pass = 0; pass < 8; ++pass) {
            int grow = row0 + mq + pass * 32;
            float4 v = make_float4(0.f, 0.f, 0.f, 0.f);
            if (grow < n) {
                v = *(const float4*)&X[(size_t)grow * K + kp + q * 4];
                if (RELU) {
                    v.x = fmaxf(v.x, 0.f); v.y = fmaxf(v.y, 0.f);
                    v.z = fmaxf(v.z, 0.f); v.w = fmaxf(v.w, 0.f);
                }
            }
            tv[pass] = v;
        }
#pragma unroll
        for (int pass = 0; pass < 8; ++pass) {
            int m = mq + pass * 32;
            As[(q * 4 + 0) * ASTR + m] = tv[pass].x;
            As[(q * 4 + 1) * ASTR + m] = tv[pass].y;
            As[(q * 4 + 2) * ASTR + m] = tv[pass].z;
            As[(q * 4 + 3) * ASTR + m] = tv[pass].w;
        }
        __syncthreads();
#pragma unroll 8
        for (int k = 0; k < 32; ++k) {
            float4 a0 = *(const float4*)&As[k * ASTR + rt * 8];
            float4 a1 = *(const float4*)&As[k * ASTR + rt * 8 + 4];
            float4 b0 = *(const float4*)&Bs[(kp + k) * FD + ct * 8];
            float4 b1 = *(const float4*)&Bs[(kp + k) * FD + ct * 8 + 4];
            float af[8] = {a0.x, a0.y, a0.z, a0.w, a1.x, a1.y, a1.z, a1.w};
            float bf[8] = {b0.x, b0.y, b0.z, b0.w, b1.x, b1.y, b1.z, b1.w};
#pragma unroll
            for (int i = 0; i < 8; ++i)
#pragma unroll
                for (int j = 0; j < 8; ++j)
                    acc[i][j] = fmaf(af[i], bf[j], acc[i][j]);
        }
    }
#pragma unroll
    for (int i = 0; i < 8; ++i) {
        int r = row0 + rt * 8 + i;
        if (r < n) {
            float sc = dinv[r];
            uint4 w;
            w.x = bf16pack(acc[i][0] * sc, acc[i][1] * sc);
            w.y = bf16pack(acc[i][2] * sc, acc[i][3] * sc);
            w.z = bf16pack(acc[i][4] * sc, acc[i][5] * sc);
            w.w = bf16pack(acc[i][6] * sc, acc[i][7] * sc);
            ((uint4*)Yb)[(size_t)r * 8 + ct] = w;   // row = 8 uint4 (128B)
        }
    }
}

// ---------------- edge aggregation (bf16 gather, f32 accumulate) -------------
__global__ __launch_bounds__(256) void k_agg(const unsigned* __restrict__ Xb,
                                             const int* __restrict__ col,
                                             const int* __restrict__ rowinfo, int cap2,
                                             const float* __restrict__ dinv,
                                             const float* __restrict__ bias,
                                             float* __restrict__ out, int n) {
    int t = blockIdx.x * 256 + threadIdx.x;
    int node = t >> 4;
    int lane = t & 15;
    if (node >= n) return;
    int info = rowinfo[node];
    int w    = (int)((unsigned)node / WN);
    int beg  = w * cap2 + (info & 0xFFFF);
    int end  = beg + (info >> 16);
    const uint2* Xv = (const uint2*)Xb;   // 16 uint2 (8B) per row
    uint2 svu = Xv[(size_t)node * 16 + lane];       // self term (early)
    float4 a0 = {0,0,0,0}, a1 = {0,0,0,0}, a2 = {0,0,0,0}, a3 = {0,0,0,0};
    int e = beg;
    for (; e + 8 <= end; e += 8) {
        int s0 = col[e],     s1 = col[e + 1], s2 = col[e + 2], s3 = col[e + 3];
        int s4 = col[e + 4], s5 = col[e + 5], s6 = col[e + 6], s7 = col[e + 7];
        uint2 u0 = Xv[(size_t)s0 * 16 + lane];
        uint2 u1 = Xv[(size_t)s1 * 16 + lane];
        uint2 u2 = Xv[(size_t)s2 * 16 + lane];
        uint2 u3 = Xv[(size_t)s3 * 16 + lane];
        uint2 u4 = Xv[(size_t)s4 * 16 + lane];
        uint2 u5 = Xv[(size_t)s5 * 16 + lane];
        uint2 u6 = Xv[(size_t)s6 * 16 + lane];
        uint2 u7 = Xv[(size_t)s7 * 16 + lane];
        float4 v0 = bf16x4(u0), v1 = bf16x4(u1), v2 = bf16x4(u2), v3 = bf16x4(u3);
        float4 v4 = bf16x4(u4), v5 = bf16x4(u5), v6 = bf16x4(u6), v7 = bf16x4(u7);
        a0.x += v0.x; a0.y += v0.y; a0.z += v0.z; a0.w += v0.w;
        a1.x += v1.x; a1.y += v1.y; a1.z += v1.z; a1.w += v1.w;
        a2.x += v2.x; a2.y += v2.y; a2.z += v2.z; a2.w += v2.w;
        a3.x += v3.x; a3.y += v3.y; a3.z += v3.z; a3.w += v3.w;
        a0.x += v4.x; a0.y += v4.y; a0.z += v4.z; a0.w += v4.w;
        a1.x += v5.x; a1.y += v5.y; a1.z += v5.z; a1.w += v5.w;
        a2.x += v6.x; a2.y += v6.y; a2.z += v6.z; a2.w += v6.w;
        a3.x += v7.x; a3.y += v7.y; a3.z += v7.z; a3.w += v7.w;
    }
    for (; e + 4 <= end; e += 4) {
        int s0 = col[e], s1 = col[e + 1], s2 = col[e + 2], s3 = col[e + 3];
        uint2 u0 = Xv[(size_t)s0 * 16 + lane];
        uint2 u1 = Xv[(size_t)s1 * 16 + lane];
        uint2 u2 = Xv[(size_t)s2 * 16 + lane];
        uint2 u3 = Xv[(size_t)s3 * 16 + lane];
        float4 v0 = bf16x4(u0), v1 = bf16x4(u1), v2 = bf16x4(u2), v3 = bf16x4(u3);
        a0.x += v0.x; a0.y += v0.y; a0.z += v0.z; a0.w += v0.w;
        a1.x += v1.x; a1.y += v1.y; a1.z += v1.z; a1.w += v1.w;
        a2.x += v2.x; a2.y += v2.y; a2.z += v2.z; a2.w += v2.w;
        a3.x += v3.x; a3.y += v3.y; a3.z += v3.z; a3.w += v3.w;
    }
    for (; e < end; ++e) {
        float4 v = bf16x4(Xv[(size_t)col[e] * 16 + lane]);
        a0.x += v.x; a0.y += v.y; a0.z += v.z; a0.w += v.w;
    }
    float4 sv = bf16x4(svu);
    float sx = a0.x + a1.x + a2.x + a3.x + sv.x;
    float sy = a0.y + a1.y + a2.y + a3.y + sv.y;
    float sz = a0.z + a1.z + a2.z + a3.z + sv.z;
    float sw = a0.w + a1.w + a2.w + a3.w + sv.w;
    float di = dinv[node];
    float4 b = ((const float4*)bias)[lane];
    float4 o;
    o.x = fmaf(di, sx, b.x);
    o.y = fmaf(di, sy, b.y);
    o.z = fmaf(di, sz, b.z);
    o.w = fmaf(di, sw, b.w);
    ((float4*)(out + (size_t)node * FD))[lane] = o;
}

// ---------------- launch ----------------

extern "C" void kernel_launch(void* const* d_in, const int* in_sizes, int n_in,
                              void* d_out, int out_size, void* d_ws, size_t ws_size,
                              hipStream_t stream) {
    const float* emb = (const float*)d_in[0];
    const float* W1  = (const float*)d_in[1];
    const float* b1  = (const float*)d_in[2];
    const float* W2  = (const float*)d_in[3];
    const float* b2  = (const float*)d_in[4];
    const int*   src = (const int*)d_in[5];
    const int*   dst = (const int*)d_in[6];

    const int D = 128;
    const int N = in_sizes[0] / D;   // 100000
    const int E = in_sizes[5];       // 1.6M
    float* out = (float*)d_out;

    const int npp  = (N + P - 1) / P;          // 12500 (< 2^14 for packing)
    const int NW   = (N + WN - 1) / WN;        // 800 windows
    const int cap1 = E / P + 16384;
    int cap2 = E / NW + 560;                   // 2560 = 10 regs * 256 thr
    if (cap2 > 2560) cap2 = 2560;              // k_sortwin register budget

    const unsigned long long M  = ((1ull << 32) + npp - 1) / npp;  // /npp
    const unsigned long long M2 = ((1ull << 32) + WN - 1) / WN;    // /125 (exact, d<2^17)

    // workspace (4B units): Ab(bf16 table) | p2 | rowinfo | dinv | gcur1 | gcur2 | p1
    unsigned* Ab   = (unsigned*)d_ws;                   // N*32 uints (rows of 64 bf16)
    int*   p2      = (int*)(Ab + (size_t)N * 32);       // NW*cap2
    int*   rowinfo = p2 + (size_t)NW * cap2;            // N
    float* dinv    = (float*)(rowinfo + N);             // N
    int*   gcur1   = (int*)(dinv + N);                  // P*G1S
    int*   gcur2   = gcur1 + P * G1S;                   // NW
    int*   p1      = gcur2 + NW;                        // P*cap1

    k_init<<<1, 1024, 0, stream>>>(gcur1, cap1, gcur2, cap2, NW);
    k_part8<<<(E + 1023) / 1024, 256, 0, stream>>>(src, dst, E, M, npp, gcur1, cap1, p1);
    int nb2 = (cap1 + 1023) / 1024;
    k_partwin<<<P * nb2, 256, 0, stream>>>(p1, gcur1, cap1, npp, M2, gcur2, cap2, p2);
    k_sortwin<<<NW, 256, 0, stream>>>(p2, gcur2, cap2, rowinfo, dinv, N);

    int gblocks = (N + 255) / 256;
    // layer 1: Ab = bf16(dinv.*(emb @ W1)); h = dinv.*(sum Ab[col] + Ab[self]) + b1
    k_gemm<128, false><<<gblocks, 256, 0, stream>>>(emb, W1, dinv, Ab, N);
    k_agg<<<(N * 16 + 255) / 256, 256, 0, stream>>>(Ab, p2, rowinfo, cap2, dinv, b1, out, N);
    // layer 2: Ab = bf16(dinv.*(relu(h) @ W2)); out = dinv.*(sum + self) + b2
    k_gemm<64, true><<<gblocks, 256, 0, stream>>>(out, W2, dinv, Ab, N);
    k_agg<<<(N * 16 + 255) / 256, 256, 0, stream>>>(Ab, p2, rowinfo, cap2, dinv, b2, out, N);
}